// Round 1
// baseline (707.920 us; speedup 1.0000x reference)
//
#include <hip/hip_runtime.h>
#include <hip/hip_bf16.h>

#define B_  16
#define S_  512
#define DM_ 512
#define H_  8
#define DK_ 64
#define DV_ 64

// ---------------------------------------------------------------------------
// QKV projection: C[b] = X[b] @ W for (X,W) in {(Q,Wq),(K,Wk),(V,Wv)}
// 512x512x512 NN GEMM, tile 128x128, BK=16, 256 threads, 8x8 per thread.
// grid (4,4,48): z = which*16 + b
// ---------------------------------------------------------------------------
__global__ __launch_bounds__(256) void k_proj(
    const float* __restrict__ Xq, const float* __restrict__ Xk, const float* __restrict__ Xv,
    const float* __restrict__ Wq, const float* __restrict__ Wk, const float* __restrict__ Wv,
    float* __restrict__ Qp, float* __restrict__ Kp, float* __restrict__ Vp)
{
    __shared__ __align__(16) float As[16][128];   // As[k][m]
    __shared__ __align__(16) float Bs[16][128];   // Bs[k][n]
    const int t = threadIdx.x;
    const int z = blockIdx.z;
    const int which = z >> 4;
    const int b     = z & 15;
    const float* X = (which == 0 ? Xq : which == 1 ? Xk : Xv) + (size_t)b * S_ * DM_;
    const float* W = (which == 0 ? Wq : which == 1 ? Wk : Wv);
    float*       C = (which == 0 ? Qp : which == 1 ? Kp : Vp) + (size_t)b * S_ * DM_;
    const int m0 = blockIdx.y * 128, n0 = blockIdx.x * 128;
    const int tx = t & 15, ty = t >> 4;

    float acc[8][8];
#pragma unroll
    for (int i = 0; i < 8; i++)
#pragma unroll
        for (int j = 0; j < 8; j++) acc[i][j] = 0.f;

    for (int k0 = 0; k0 < 512; k0 += 16) {
        // A tile 128x16 -> As[k][m] (transposed scatter)
#pragma unroll
        for (int i = 0; i < 2; i++) {
            int idx = t + i * 256;            // 512 float4 slots
            int row = idx >> 2;               // 0..127
            int c4  = (idx & 3) << 2;         // 0,4,8,12
            float4 v = *(const float4*)&X[(size_t)(m0 + row) * DM_ + k0 + c4];
            As[c4 + 0][row] = v.x; As[c4 + 1][row] = v.y;
            As[c4 + 2][row] = v.z; As[c4 + 3][row] = v.w;
        }
        // B tile 16x128 -> Bs[k][n] (natural, vector writes)
#pragma unroll
        for (int i = 0; i < 2; i++) {
            int idx = t + i * 256;
            int row = idx >> 5;               // 0..15
            int c   = (idx & 31) << 2;        // 0..124
            *(float4*)&Bs[row][c] = *(const float4*)&W[(size_t)(k0 + row) * DM_ + n0 + c];
        }
        __syncthreads();
#pragma unroll
        for (int kk = 0; kk < 16; kk++) {
            float4 a0 = *(float4*)&As[kk][ty * 8];
            float4 a1 = *(float4*)&As[kk][ty * 8 + 4];
            float4 b0 = *(float4*)&Bs[kk][tx * 8];
            float4 b1 = *(float4*)&Bs[kk][tx * 8 + 4];
            float av[8] = {a0.x, a0.y, a0.z, a0.w, a1.x, a1.y, a1.z, a1.w};
            float bv[8] = {b0.x, b0.y, b0.z, b0.w, b1.x, b1.y, b1.z, b1.w};
#pragma unroll
            for (int i = 0; i < 8; i++)
#pragma unroll
                for (int j = 0; j < 8; j++) acc[i][j] += av[i] * bv[j];
        }
        __syncthreads();
    }
#pragma unroll
    for (int i = 0; i < 8; i++) {
        int row = m0 + ty * 8 + i;
        float4 o0 = make_float4(acc[i][0], acc[i][1], acc[i][2], acc[i][3]);
        float4 o1 = make_float4(acc[i][4], acc[i][5], acc[i][6], acc[i][7]);
        *(float4*)&C[(size_t)row * DM_ + n0 + tx * 8]     = o0;
        *(float4*)&C[(size_t)row * DM_ + n0 + tx * 8 + 4] = o1;
    }
}

// ---------------------------------------------------------------------------
// scores[b,h,q,k] = (Q[b,q,h,:] . K[b,k,h,:]) * 0.125 + res[b,h,q,k],
// then mask -> -1e9. Writes into d_out scores region.
// NT GEMM K=64, tile 64x64, 256 threads, 4x4 per thread. grid (8,8,128)
// ---------------------------------------------------------------------------
__global__ __launch_bounds__(256) void k_scores(
    const float* __restrict__ Qp, const float* __restrict__ Kp,
    const float* __restrict__ res, const unsigned char* __restrict__ mask,
    float* __restrict__ scores)
{
    __shared__ __align__(16) float Qs[64][68];   // Qs[e][q]
    __shared__ __align__(16) float Ks[64][68];   // Ks[e][k]
    const int t  = threadIdx.x;
    const int bh = blockIdx.z;
    const int b  = bh >> 3, h = bh & 7;
    const int q0 = blockIdx.y * 64, k0 = blockIdx.x * 64;
    const float* Qb = Qp + (size_t)b * S_ * DM_ + h * 64;
    const float* Kb = Kp + (size_t)b * S_ * DM_ + h * 64;

#pragma unroll
    for (int i = 0; i < 4; i++) {
        int idx = t + i * 256;                // 1024 float4 slots
        int row = idx >> 4;                   // 0..63
        int c4  = (idx & 15) << 2;            // 0..60
        float4 v = *(const float4*)&Qb[(size_t)(q0 + row) * DM_ + c4];
        Qs[c4 + 0][row] = v.x; Qs[c4 + 1][row] = v.y;
        Qs[c4 + 2][row] = v.z; Qs[c4 + 3][row] = v.w;
        float4 w = *(const float4*)&Kb[(size_t)(k0 + row) * DM_ + c4];
        Ks[c4 + 0][row] = w.x; Ks[c4 + 1][row] = w.y;
        Ks[c4 + 2][row] = w.z; Ks[c4 + 3][row] = w.w;
    }
    __syncthreads();
    const int tx = t & 15, ty = t >> 4;
    float acc[4][4] = {};
#pragma unroll 16
    for (int e = 0; e < 64; e++) {
        float4 a  = *(float4*)&Qs[e][ty * 4];
        float4 bb = *(float4*)&Ks[e][tx * 4];
        float av[4] = {a.x, a.y, a.z, a.w};
        float bv[4] = {bb.x, bb.y, bb.z, bb.w};
#pragma unroll
        for (int i = 0; i < 4; i++)
#pragma unroll
            for (int j = 0; j < 4; j++) acc[i][j] += av[i] * bv[j];
    }
    const size_t sbase = ((size_t)bh * S_ + q0) * S_ + k0;
    const size_t mbase = ((size_t)b * S_ + q0) * S_ + k0;
#pragma unroll
    for (int i = 0; i < 4; i++) {
        int q = ty * 4 + i;
        float4 r  = *(const float4*)&res[sbase + (size_t)q * S_ + tx * 4];
        uchar4 mk = *(const uchar4*)&mask[mbase + (size_t)q * S_ + tx * 4];
        float4 o;
        o.x = mk.x ? -1e9f : acc[i][0] * 0.125f + r.x;
        o.y = mk.y ? -1e9f : acc[i][1] * 0.125f + r.y;
        o.z = mk.z ? -1e9f : acc[i][2] * 0.125f + r.z;
        o.w = mk.w ? -1e9f : acc[i][3] * 0.125f + r.w;
        *(float4*)&scores[sbase + (size_t)q * S_ + tx * 4] = o;
    }
}

// ---------------------------------------------------------------------------
// Column softmax over the QUERY axis (reference softmaxes axis=3 == q).
// Partial online (m,s) per (b,h,k) over a 128-row q-chunk. grid 512, block 512
// ---------------------------------------------------------------------------
__global__ __launch_bounds__(512) void k_sm_partial(
    const float* __restrict__ scores, float* __restrict__ pm, float* __restrict__ ps)
{
    const int z  = blockIdx.x;          // bh*4 + qc
    const int bh = z >> 2, qc = z & 3;
    const int k  = threadIdx.x;
    const float* sc = scores + ((size_t)bh * S_ + qc * 128) * S_ + k;
    float m = -3.4e38f, s = 0.f;
    for (int q = 0; q < 128; q++) {
        float x  = sc[(size_t)q * S_];
        float nm = fmaxf(m, x);
        s = s * __expf(m - nm) + __expf(x - nm);
        m = nm;
    }
    pm[(size_t)z * S_ + k] = m;
    ps[(size_t)z * S_ + k] = s;
}

__global__ __launch_bounds__(256) void k_sm_combine(
    const float* __restrict__ pm, const float* __restrict__ ps,
    float* __restrict__ colm, float* __restrict__ colinv)
{
    const int idx = blockIdx.x * 256 + threadIdx.x;   // 65536 = B*H*S
    const int bh  = idx >> 9, k = idx & 511;
    float m = -3.4e38f;
#pragma unroll
    for (int c = 0; c < 4; c++) m = fmaxf(m, pm[((size_t)bh * 4 + c) * S_ + k]);
    float s = 0.f;
#pragma unroll
    for (int c = 0; c < 4; c++)
        s += ps[((size_t)bh * 4 + c) * S_ + k] * __expf(pm[((size_t)bh * 4 + c) * S_ + k] - m);
    colm[idx]   = m;
    colinv[idx] = 1.0f / s;
}

// ---------------------------------------------------------------------------
// context[b,q,h*64+v] = sum_k exp(scores[b,h,q,k]-m_k)*inv_k * V[b,k,h*64+v]
// tile 64(q) x 64(v), K-loop over 512 in 64 chunks. grid (8,128)
// ---------------------------------------------------------------------------
__global__ __launch_bounds__(256) void k_ctx(
    const float* __restrict__ scores, const float* __restrict__ Vp,
    const float* __restrict__ colm, const float* __restrict__ colinv,
    float* __restrict__ ctx)
{
    __shared__ __align__(16) float Ps[64][68];   // Ps[k][q]
    __shared__ __align__(16) float Vs[64][68];   // Vs[k][v]
    const int t  = threadIdx.x;
    const int bh = blockIdx.y, b = bh >> 3, h = bh & 7;
    const int q0 = blockIdx.x * 64;
    const int tx = t & 15, ty = t >> 4;
    const float* Vb = Vp + (size_t)b * S_ * DM_ + h * 64;
    float acc[4][4] = {};

    for (int k0 = 0; k0 < 512; k0 += 64) {
        const int c4 = (t & 15) << 2;     // this thread's k-subcolumn (fixed)
        float4 mv = *(const float4*)&colm  [(size_t)bh * S_ + k0 + c4];
        float4 iv = *(const float4*)&colinv[(size_t)bh * S_ + k0 + c4];
#pragma unroll
        for (int i = 0; i < 4; i++) {
            int row = (t >> 4) + i * 16;  // q-row in tile
            float4 sv = *(const float4*)&scores[((size_t)bh * S_ + q0 + row) * S_ + k0 + c4];
            Ps[c4 + 0][row] = __expf(sv.x - mv.x) * iv.x;
            Ps[c4 + 1][row] = __expf(sv.y - mv.y) * iv.y;
            Ps[c4 + 2][row] = __expf(sv.z - mv.z) * iv.z;
            Ps[c4 + 3][row] = __expf(sv.w - mv.w) * iv.w;
        }
#pragma unroll
        for (int i = 0; i < 4; i++) {
            int idx = t + i * 256;
            int row = idx >> 4;
            int cc  = (idx & 15) << 2;
            *(float4*)&Vs[row][cc] = *(const float4*)&Vb[(size_t)(k0 + row) * DM_ + cc];
        }
        __syncthreads();
#pragma unroll 16
        for (int kk = 0; kk < 64; kk++) {
            float4 a  = *(float4*)&Ps[kk][ty * 4];
            float4 bv = *(float4*)&Vs[kk][tx * 4];
            float av[4] = {a.x, a.y, a.z, a.w};
            float vv[4] = {bv.x, bv.y, bv.z, bv.w};
#pragma unroll
            for (int i = 0; i < 4; i++)
#pragma unroll
                for (int j = 0; j < 4; j++) acc[i][j] += av[i] * vv[j];
        }
        __syncthreads();
    }
#pragma unroll
    for (int i = 0; i < 4; i++) {
        int q = q0 + ty * 4 + i;
        *(float4*)&ctx[((size_t)b * S_ + q) * DM_ + h * 64 + tx * 4] =
            make_float4(acc[i][0], acc[i][1], acc[i][2], acc[i][3]);
    }
}

// ---------------------------------------------------------------------------
// out = ctx @ W_fc + input_Q   (512x512x512 NN + residual). grid (4,4,16)
// ---------------------------------------------------------------------------
__global__ __launch_bounds__(256) void k_outproj(
    const float* __restrict__ A, const float* __restrict__ W,
    const float* __restrict__ resid, float* __restrict__ C)
{
    __shared__ __align__(16) float As[16][128];
    __shared__ __align__(16) float Bs[16][128];
    const int t = threadIdx.x;
    const int b = blockIdx.z;
    const float* Ab = A + (size_t)b * S_ * DM_;
    const float* Rb = resid + (size_t)b * S_ * DM_;
    float*       Cb = C + (size_t)b * S_ * DM_;
    const int m0 = blockIdx.y * 128, n0 = blockIdx.x * 128;
    const int tx = t & 15, ty = t >> 4;

    float acc[8][8];
#pragma unroll
    for (int i = 0; i < 8; i++)
#pragma unroll
        for (int j = 0; j < 8; j++) acc[i][j] = 0.f;

    for (int k0 = 0; k0 < 512; k0 += 16) {
#pragma unroll
        for (int i = 0; i < 2; i++) {
            int idx = t + i * 256;
            int row = idx >> 2;
            int c4  = (idx & 3) << 2;
            float4 v = *(const float4*)&Ab[(size_t)(m0 + row) * DM_ + k0 + c4];
            As[c4 + 0][row] = v.x; As[c4 + 1][row] = v.y;
            As[c4 + 2][row] = v.z; As[c4 + 3][row] = v.w;
        }
#pragma unroll
        for (int i = 0; i < 2; i++) {
            int idx = t + i * 256;
            int row = idx >> 5;
            int c   = (idx & 31) << 2;
            *(float4*)&Bs[row][c] = *(const float4*)&W[(size_t)(k0 + row) * DM_ + n0 + c];
        }
        __syncthreads();
#pragma unroll
        for (int kk = 0; kk < 16; kk++) {
            float4 a0 = *(float4*)&As[kk][ty * 8];
            float4 a1 = *(float4*)&As[kk][ty * 8 + 4];
            float4 b0 = *(float4*)&Bs[kk][tx * 8];
            float4 b1 = *(float4*)&Bs[kk][tx * 8 + 4];
            float av[8] = {a0.x, a0.y, a0.z, a0.w, a1.x, a1.y, a1.z, a1.w};
            float bv[8] = {b0.x, b0.y, b0.z, b0.w, b1.x, b1.y, b1.z, b1.w};
#pragma unroll
            for (int i = 0; i < 8; i++)
#pragma unroll
                for (int j = 0; j < 8; j++) acc[i][j] += av[i] * bv[j];
        }
        __syncthreads();
    }
#pragma unroll
    for (int i = 0; i < 8; i++) {
        int row = m0 + ty * 8 + i;
        float4 r0 = *(const float4*)&Rb[(size_t)row * DM_ + n0 + tx * 8];
        float4 r1 = *(const float4*)&Rb[(size_t)row * DM_ + n0 + tx * 8 + 4];
        float4 o0 = make_float4(acc[i][0] + r0.x, acc[i][1] + r0.y, acc[i][2] + r0.z, acc[i][3] + r0.w);
        float4 o1 = make_float4(acc[i][4] + r1.x, acc[i][5] + r1.y, acc[i][6] + r1.z, acc[i][7] + r1.w);
        *(float4*)&Cb[(size_t)row * DM_ + n0 + tx * 8]     = o0;
        *(float4*)&Cb[(size_t)row * DM_ + n0 + tx * 8 + 4] = o1;
    }
}

// ---------------------------------------------------------------------------
// In-place LayerNorm over last dim (512). One block (512 thr) per row.
// ---------------------------------------------------------------------------
__global__ __launch_bounds__(512) void k_ln(
    float* __restrict__ out, const float* __restrict__ gamma, const float* __restrict__ beta)
{
    __shared__ float r1[8], r2[8];
    const int row = blockIdx.x;
    const int t   = threadIdx.x;
    float x  = out[(size_t)row * DM_ + t];
    float s1 = x, s2 = x * x;
#pragma unroll
    for (int o = 32; o > 0; o >>= 1) {
        s1 += __shfl_xor(s1, o);
        s2 += __shfl_xor(s2, o);
    }
    const int lane = t & 63, w = t >> 6;
    if (lane == 0) { r1[w] = s1; r2[w] = s2; }
    __syncthreads();
    float tot1 = 0.f, tot2 = 0.f;
#pragma unroll
    for (int i = 0; i < 8; i++) { tot1 += r1[i]; tot2 += r2[i]; }
    const float mu   = tot1 * (1.0f / 512.0f);
    const float var  = tot2 * (1.0f / 512.0f) - mu * mu;
    const float rstd = rsqrtf(var + 1e-5f);
    out[(size_t)row * DM_ + t] = (x - mu) * rstd * gamma[t] + beta[t];
}

// ---------------------------------------------------------------------------
extern "C" void kernel_launch(void* const* d_in, const int* in_sizes, int n_in,
                              void* d_out, int out_size, void* d_ws, size_t ws_size,
                              hipStream_t stream)
{
    const float*         inQ   = (const float*)d_in[0];
    const float*         inK   = (const float*)d_in[1];
    const float*         inV   = (const float*)d_in[2];
    const unsigned char* mask  = (const unsigned char*)d_in[3];
    const float*         res   = (const float*)d_in[4];
    const float*         Wq    = (const float*)d_in[5];
    const float*         Wk    = (const float*)d_in[6];
    const float*         Wv    = (const float*)d_in[7];
    const float*         Wfc   = (const float*)d_in[8];
    const float*         gamma = (const float*)d_in[9];
    const float*         beta  = (const float*)d_in[10];

    float* out    = (float*)d_out;                      // B*S*DM = 4,194,304
    float* scores = out + (size_t)B_ * S_ * DM_;        // B*H*S*S = 33,554,432

    float* ws     = (float*)d_ws;
    float* Qp     = ws;                                  // 4,194,304
    float* Kp     = Qp + (size_t)B_ * S_ * DM_;          // 4,194,304
    float* Vp     = Kp + (size_t)B_ * S_ * DM_;          // 4,194,304
    float* ctx    = Vp + (size_t)B_ * S_ * DM_;          // 4,194,304
    float* colm   = ctx + (size_t)B_ * S_ * DM_;         // 65,536
    float* colinv = colm + (size_t)B_ * H_ * S_;         // 65,536
    float* pm     = colinv + (size_t)B_ * H_ * S_;       // 262,144
    float* ps     = pm + (size_t)B_ * H_ * S_ * 4;       // 262,144
    // total ws: 17,432,576 floats = 69.7 MB

    hipLaunchKernelGGL(k_proj,       dim3(4, 4, 48),  dim3(256), 0, stream,
                       inQ, inK, inV, Wq, Wk, Wv, Qp, Kp, Vp);
    hipLaunchKernelGGL(k_scores,     dim3(8, 8, 128), dim3(256), 0, stream,
                       Qp, Kp, res, mask, scores);
    hipLaunchKernelGGL(k_sm_partial, dim3(512),       dim3(512), 0, stream,
                       scores, pm, ps);
    hipLaunchKernelGGL(k_sm_combine, dim3(256),       dim3(256), 0, stream,
                       pm, ps, colm, colinv);
    hipLaunchKernelGGL(k_ctx,        dim3(8, 128),    dim3(256), 0, stream,
                       scores, Vp, colm, colinv, ctx);
    hipLaunchKernelGGL(k_outproj,    dim3(4, 4, 16),  dim3(256), 0, stream,
                       ctx, Wfc, inQ, out);
    hipLaunchKernelGGL(k_ln,         dim3(8192),      dim3(512), 0, stream,
                       out, gamma, beta);
}

// Round 2
// 501.233 us; speedup vs baseline: 1.4124x; 1.4124x over previous
//
#include <hip/hip_runtime.h>
#include <hip/hip_bf16.h>

#define B_  16
#define S_  512
#define DM_ 512
#define H_  8

typedef short  bf16x8 __attribute__((ext_vector_type(8)));
typedef float  f32x4  __attribute__((ext_vector_type(4)));

__device__ __forceinline__ unsigned short f2b(float x) {
    __hip_bfloat16 h = __float2bfloat16(x);
    return __builtin_bit_cast(unsigned short, h);
}

// LDS tiles: rows of 64 bf16 = 128 B = 8 slots of 16 B. XOR swizzle on slot.
__device__ __forceinline__ bf16x8 ld_frag(const unsigned short* base, int row, int slot) {
    return *(const bf16x8*)((const char*)base + row * 128 + (((slot) ^ (row & 7)) << 4));
}

// ---------------------------------------------------------------------------
// Cast + transpose weights: Wt[n][k] (bf16) = W[k][n] (fp32). grid (8,8,4)
// ---------------------------------------------------------------------------
__global__ __launch_bounds__(256) void k_cast_wt(
    const float* __restrict__ Wq, const float* __restrict__ Wk,
    const float* __restrict__ Wv, const float* __restrict__ Wfc,
    unsigned short* __restrict__ Wtq, unsigned short* __restrict__ Wtk,
    unsigned short* __restrict__ Wtv, unsigned short* __restrict__ Wtfc)
{
    __shared__ float T[64][68];
    const int t = threadIdx.x, mz = blockIdx.z;
    const float* src = (mz == 0 ? Wq : mz == 1 ? Wk : mz == 2 ? Wv : Wfc);
    unsigned short* dst = (mz == 0 ? Wtq : mz == 1 ? Wtk : mz == 2 ? Wtv : Wtfc);
    const int r0 = blockIdx.y * 64, c0 = blockIdx.x * 64;   // r0: k, c0: n
#pragma unroll
    for (int i = 0; i < 4; i++) {
        int f = i * 256 + t, row = f >> 4, c4 = (f & 15) * 4;
        float4 v = *(const float4*)&src[(size_t)(r0 + row) * DM_ + c0 + c4];
        T[row][c4 + 0] = v.x; T[row][c4 + 1] = v.y; T[row][c4 + 2] = v.z; T[row][c4 + 3] = v.w;
    }
    __syncthreads();
#pragma unroll
    for (int i = 0; i < 4; i++) {
        int f = i * 256 + t, n = f >> 4, k4 = (f & 15) * 4;
        ushort4 o;
        o.x = f2b(T[k4 + 0][n]); o.y = f2b(T[k4 + 1][n]);
        o.z = f2b(T[k4 + 2][n]); o.w = f2b(T[k4 + 3][n]);
        *(ushort4*)&dst[(size_t)(c0 + n) * DM_ + r0 + k4] = o;
    }
}

// ---------------------------------------------------------------------------
// QKV projection, bf16 MFMA. C[b] = X[b] @ W. 128x128 tile, BK=64.
// grid (4,4,48): z = which*16 + b. Output bf16 [b][s][dm].
// ---------------------------------------------------------------------------
__global__ __launch_bounds__(256) void k_proj(
    const float* __restrict__ Xq, const float* __restrict__ Xk, const float* __restrict__ Xv,
    const unsigned short* __restrict__ Wtq, const unsigned short* __restrict__ Wtk,
    const unsigned short* __restrict__ Wtv,
    unsigned short* __restrict__ Qp, unsigned short* __restrict__ Kp, unsigned short* __restrict__ Vp)
{
    __shared__ __align__(16) unsigned short As[128 * 64];
    __shared__ __align__(16) unsigned short Bs[128 * 64];
    const int t = threadIdx.x;
    const int z = blockIdx.z, which = z >> 4, b = z & 15;
    const float* X = (which == 0 ? Xq : which == 1 ? Xk : Xv) + (size_t)b * S_ * DM_;
    const unsigned short* Wt = (which == 0 ? Wtq : which == 1 ? Wtk : Wtv);
    unsigned short* C = (which == 0 ? Qp : which == 1 ? Kp : Vp) + (size_t)b * S_ * DM_;
    const int m0 = blockIdx.y * 128, n0 = blockIdx.x * 128;
    const int lane = t & 63, w = t >> 6, wr = w >> 1, wc = w & 1, lr = lane & 15, lg = lane >> 4;

    f32x4 acc[4][4];
#pragma unroll
    for (int i = 0; i < 4; i++)
#pragma unroll
        for (int j = 0; j < 4; j++) acc[i][j] = (f32x4){0.f, 0.f, 0.f, 0.f};

    for (int k0 = 0; k0 < DM_; k0 += 64) {
#pragma unroll
        for (int i = 0; i < 8; i++) {   // A: fp32 -> bf16, 128x64
            int f = i * 256 + t, row = f >> 4, c4 = (f & 15) * 4;
            float4 v = *(const float4*)&X[(size_t)(m0 + row) * DM_ + k0 + c4];
            ushort4 o; o.x = f2b(v.x); o.y = f2b(v.y); o.z = f2b(v.z); o.w = f2b(v.w);
            int off = ((f & 15) * 8) ^ ((row & 7) << 4);
            *(ushort4*)((char*)As + row * 128 + off) = o;
        }
#pragma unroll
        for (int i = 0; i < 4; i++) {   // B: bf16 Wt rows, 128x64
            int f = i * 256 + t, row = f >> 3, slot = f & 7;
            uint4 v = *(const uint4*)&Wt[(size_t)(n0 + row) * DM_ + k0 + slot * 8];
            *(uint4*)((char*)Bs + row * 128 + ((slot * 16) ^ ((row & 7) << 4))) = v;
        }
        __syncthreads();
#pragma unroll
        for (int es = 0; es < 2; es++) {
            bf16x8 af[4], bg[4];
#pragma unroll
            for (int fi = 0; fi < 4; fi++) af[fi] = ld_frag(As, wr * 64 + fi * 16 + lr, es * 4 + lg);
#pragma unroll
            for (int fj = 0; fj < 4; fj++) bg[fj] = ld_frag(Bs, wc * 64 + fj * 16 + lr, es * 4 + lg);
#pragma unroll
            for (int fi = 0; fi < 4; fi++)
#pragma unroll
                for (int fj = 0; fj < 4; fj++)
                    acc[fi][fj] = __builtin_amdgcn_mfma_f32_16x16x32_bf16(af[fi], bg[fj], acc[fi][fj], 0, 0, 0);
        }
        __syncthreads();
    }
#pragma unroll
    for (int fi = 0; fi < 4; fi++)
#pragma unroll
        for (int fj = 0; fj < 4; fj++)
#pragma unroll
            for (int r = 0; r < 4; r++) {
                int row = m0 + wr * 64 + fi * 16 + lg * 4 + r;
                int col = n0 + wc * 64 + fj * 16 + lr;
                C[(size_t)row * DM_ + col] = f2b(acc[fi][fj][r]);
            }
}

// ---------------------------------------------------------------------------
// Transpose V: Vt[b*8+h][v][s] = Vp[b][s][h*64+v]. grid (8,128)
// ---------------------------------------------------------------------------
__global__ __launch_bounds__(256) void k_tv(
    const unsigned short* __restrict__ Vp, unsigned short* __restrict__ Vt)
{
    __shared__ unsigned short T[64][68];
    const int t = threadIdx.x;
    const int bh = blockIdx.y, b = bh >> 3, h = bh & 7;
    const int s0 = blockIdx.x * 64;
#pragma unroll
    for (int i = 0; i < 4; i++) {
        int f = i * 256 + t, row = f >> 4, c4 = (f & 15) * 4;
        ushort4 v = *(const ushort4*)&Vp[((size_t)b * S_ + s0 + row) * DM_ + h * 64 + c4];
        T[row][c4 + 0] = v.x; T[row][c4 + 1] = v.y; T[row][c4 + 2] = v.z; T[row][c4 + 3] = v.w;
    }
    __syncthreads();
#pragma unroll
    for (int i = 0; i < 4; i++) {
        int f = i * 256 + t, v = f >> 4, s4 = (f & 15) * 4;
        ushort4 o;
        o.x = T[s4 + 0][v]; o.y = T[s4 + 1][v]; o.z = T[s4 + 2][v]; o.w = T[s4 + 3][v];
        *(ushort4*)&Vt[((size_t)bh * 64 + v) * S_ + s0 + s4] = o;
    }
}

// ---------------------------------------------------------------------------
// scores = QK^T*0.125 + res, mask -> -1e9; fused per-column (query-axis)
// softmax partials. 128x128 tile, e=64 staged once. grid (4 kt, 4 qt, 128 bh)
// ---------------------------------------------------------------------------
__global__ __launch_bounds__(256) void k_scores(
    const unsigned short* __restrict__ Qp, const unsigned short* __restrict__ Kp,
    const float* __restrict__ res, const unsigned char* __restrict__ mask,
    float* __restrict__ scores, float* __restrict__ pm, float* __restrict__ ps)
{
    __shared__ __align__(16) unsigned short Qs[128 * 64];
    __shared__ __align__(16) unsigned short Ks[128 * 64];
    __shared__ float smax[2][128], ssum[2][128];
    const int t = threadIdx.x;
    const int bh = blockIdx.z, b = bh >> 3, h = bh & 7;
    const int q0 = blockIdx.y * 128, k0 = blockIdx.x * 128;
    const int lane = t & 63, w = t >> 6, wr = w >> 1, wc = w & 1, lr = lane & 15, lg = lane >> 4;

#pragma unroll
    for (int i = 0; i < 4; i++) {
        int f = i * 256 + t, row = f >> 3, slot = f & 7;
        uint4 q = *(const uint4*)&Qp[((size_t)b * S_ + q0 + row) * DM_ + h * 64 + slot * 8];
        *(uint4*)((char*)Qs + row * 128 + ((slot * 16) ^ ((row & 7) << 4))) = q;
        uint4 k = *(const uint4*)&Kp[((size_t)b * S_ + k0 + row) * DM_ + h * 64 + slot * 8];
        *(uint4*)((char*)Ks + row * 128 + ((slot * 16) ^ ((row & 7) << 4))) = k;
    }
    __syncthreads();

    f32x4 acc[4][4];
#pragma unroll
    for (int i = 0; i < 4; i++)
#pragma unroll
        for (int j = 0; j < 4; j++) acc[i][j] = (f32x4){0.f, 0.f, 0.f, 0.f};
#pragma unroll
    for (int es = 0; es < 2; es++) {
        bf16x8 af[4], bg[4];
#pragma unroll
        for (int fi = 0; fi < 4; fi++) af[fi] = ld_frag(Qs, wr * 64 + fi * 16 + lr, es * 4 + lg);
#pragma unroll
        for (int fj = 0; fj < 4; fj++) bg[fj] = ld_frag(Ks, wc * 64 + fj * 16 + lr, es * 4 + lg);
#pragma unroll
        for (int fi = 0; fi < 4; fi++)
#pragma unroll
            for (int fj = 0; fj < 4; fj++)
                acc[fi][fj] = __builtin_amdgcn_mfma_f32_16x16x32_bf16(af[fi], bg[fj], acc[fi][fj], 0, 0, 0);
    }

    // epilogue: x = acc*0.125 + res (mask -> -1e9); write scores; keep x in acc
#pragma unroll
    for (int fi = 0; fi < 4; fi++)
#pragma unroll
        for (int fj = 0; fj < 4; fj++)
#pragma unroll
            for (int r = 0; r < 4; r++) {
                int qrow = q0 + wr * 64 + fi * 16 + lg * 4 + r;
                int kcol = k0 + wc * 64 + fj * 16 + lr;
                size_t sidx = ((size_t)bh * S_ + qrow) * S_ + kcol;
                float x = acc[fi][fj][r] * 0.125f + res[sidx];
                if (mask[((size_t)b * S_ + qrow) * S_ + kcol]) x = -1e9f;
                scores[sidx] = x;
                acc[fi][fj][r] = x;
            }

    // per-column (over q) partial max/expsum within this block's 128 rows
#pragma unroll
    for (int fj = 0; fj < 4; fj++) {
        float m = -3.4e38f;
#pragma unroll
        for (int fi = 0; fi < 4; fi++)
#pragma unroll
            for (int r = 0; r < 4; r++) m = fmaxf(m, acc[fi][fj][r]);
        m = fmaxf(m, __shfl_xor(m, 16));
        m = fmaxf(m, __shfl_xor(m, 32));
        float s = 0.f;
#pragma unroll
        for (int fi = 0; fi < 4; fi++)
#pragma unroll
            for (int r = 0; r < 4; r++) s += __expf(acc[fi][fj][r] - m);
        s += __shfl_xor(s, 16);
        s += __shfl_xor(s, 32);
        if (lg == 0) {
            int c = wc * 64 + fj * 16 + lr;
            smax[wr][c] = m; ssum[wr][c] = s;
        }
    }
    __syncthreads();
    if (t < 128) {
        float m0v = smax[0][t], m1v = smax[1][t];
        float M = fmaxf(m0v, m1v);
        float S = ssum[0][t] * __expf(m0v - M) + ssum[1][t] * __expf(m1v - M);
        size_t idx = ((size_t)blockIdx.y * 128 + bh) * S_ + k0 + t;
        pm[idx] = M; ps[idx] = S;
    }
}

// ---------------------------------------------------------------------------
// Combine 4 q-chunk partials -> colm, colinv. grid 256 x 256
// ---------------------------------------------------------------------------
__global__ __launch_bounds__(256) void k_sm_combine(
    const float* __restrict__ pm, const float* __restrict__ ps,
    float* __restrict__ colm, float* __restrict__ colinv)
{
    const int i = blockIdx.x * 256 + threadIdx.x;   // bh*512 + k
    const int bh = i >> 9, k = i & 511;
    float m = -3.4e38f;
#pragma unroll
    for (int qt = 0; qt < 4; qt++) m = fmaxf(m, pm[((size_t)qt * 128 + bh) * S_ + k]);
    float s = 0.f;
#pragma unroll
    for (int qt = 0; qt < 4; qt++)
        s += ps[((size_t)qt * 128 + bh) * S_ + k] * __expf(pm[((size_t)qt * 128 + bh) * S_ + k] - m);
    colm[i] = m;
    colinv[i] = 1.0f / s;
}

// ---------------------------------------------------------------------------
// context: D[q][v] = sum_s P[q][s] V[s][v], P = exp(score-colm)*colinv (bf16).
// BM=256 q, N=64 v, BK=64. grid (2, 128). Output ctx bf16 [b][q][dm].
// ---------------------------------------------------------------------------
__global__ __launch_bounds__(256) void k_ctx(
    const float* __restrict__ scores, const unsigned short* __restrict__ Vt,
    const float* __restrict__ colm, const float* __restrict__ colinv,
    unsigned short* __restrict__ ctx)
{
    __shared__ __align__(16) unsigned short Ps[256 * 64];
    __shared__ __align__(16) unsigned short Vs[64 * 64];
    const int t = threadIdx.x;
    const int bh = blockIdx.y, b = bh >> 3, h = bh & 7;
    const int q0 = blockIdx.x * 256;
    const int lane = t & 63, w = t >> 6, lr = lane & 15, lg = lane >> 4;

    f32x4 acc[4][4];
#pragma unroll
    for (int i = 0; i < 4; i++)
#pragma unroll
        for (int j = 0; j < 4; j++) acc[i][j] = (f32x4){0.f, 0.f, 0.f, 0.f};

    for (int k0 = 0; k0 < S_; k0 += 64) {
#pragma unroll
        for (int i = 0; i < 16; i++) {   // P staging: fp32 scores -> exp -> bf16
            int f = i * 256 + t, row = f >> 4, c4 = (f & 15) * 4;
            float4 sv = *(const float4*)&scores[((size_t)bh * S_ + q0 + row) * S_ + k0 + c4];
            float4 mv = *(const float4*)&colm[(size_t)bh * S_ + k0 + c4];
            float4 iv = *(const float4*)&colinv[(size_t)bh * S_ + k0 + c4];
            ushort4 o;
            o.x = f2b(__expf(sv.x - mv.x) * iv.x);
            o.y = f2b(__expf(sv.y - mv.y) * iv.y);
            o.z = f2b(__expf(sv.z - mv.z) * iv.z);
            o.w = f2b(__expf(sv.w - mv.w) * iv.w);
            int off = ((f & 15) * 8) ^ ((row & 7) << 4);
            *(ushort4*)((char*)Ps + row * 128 + off) = o;
        }
#pragma unroll
        for (int i = 0; i < 2; i++) {    // V staging (already transposed: rows v, cols s)
            int f = i * 256 + t, row = f >> 3, slot = f & 7;
            uint4 v = *(const uint4*)&Vt[((size_t)bh * 64 + row) * S_ + k0 + slot * 8];
            *(uint4*)((char*)Vs + row * 128 + ((slot * 16) ^ ((row & 7) << 4))) = v;
        }
        __syncthreads();
#pragma unroll
        for (int es = 0; es < 2; es++) {
            bf16x8 af[4], bg[4];
#pragma unroll
            for (int fi = 0; fi < 4; fi++) af[fi] = ld_frag(Ps, w * 64 + fi * 16 + lr, es * 4 + lg);
#pragma unroll
            for (int fj = 0; fj < 4; fj++) bg[fj] = ld_frag(Vs, fj * 16 + lr, es * 4 + lg);
#pragma unroll
            for (int fi = 0; fi < 4; fi++)
#pragma unroll
                for (int fj = 0; fj < 4; fj++)
                    acc[fi][fj] = __builtin_amdgcn_mfma_f32_16x16x32_bf16(af[fi], bg[fj], acc[fi][fj], 0, 0, 0);
        }
        __syncthreads();
    }
#pragma unroll
    for (int fi = 0; fi < 4; fi++)
#pragma unroll
        for (int fj = 0; fj < 4; fj++)
#pragma unroll
            for (int r = 0; r < 4; r++) {
                int q = q0 + w * 64 + fi * 16 + lg * 4 + r;
                int col = h * 64 + fj * 16 + lr;
                ctx[((size_t)b * S_ + q) * DM_ + col] = f2b(acc[fi][fj][r]);
            }
}

// ---------------------------------------------------------------------------
// out = ctx @ W_fc + input_Q (fp32 out). 128x128 tile, BK=64. grid (4,4,16)
// ---------------------------------------------------------------------------
__global__ __launch_bounds__(256) void k_outproj(
    const unsigned short* __restrict__ ctxb, const unsigned short* __restrict__ Wtfc,
    const float* __restrict__ resid, float* __restrict__ out)
{
    __shared__ __align__(16) unsigned short As[128 * 64];
    __shared__ __align__(16) unsigned short Bs[128 * 64];
    const int t = threadIdx.x, b = blockIdx.z;
    const int m0 = blockIdx.y * 128, n0 = blockIdx.x * 128;
    const int lane = t & 63, w = t >> 6, wr = w >> 1, wc = w & 1, lr = lane & 15, lg = lane >> 4;

    f32x4 acc[4][4];
#pragma unroll
    for (int i = 0; i < 4; i++)
#pragma unroll
        for (int j = 0; j < 4; j++) acc[i][j] = (f32x4){0.f, 0.f, 0.f, 0.f};

    for (int k0 = 0; k0 < DM_; k0 += 64) {
#pragma unroll
        for (int i = 0; i < 4; i++) {
            int f = i * 256 + t, row = f >> 3, slot = f & 7;
            uint4 a = *(const uint4*)&ctxb[((size_t)b * S_ + m0 + row) * DM_ + k0 + slot * 8];
            *(uint4*)((char*)As + row * 128 + ((slot * 16) ^ ((row & 7) << 4))) = a;
            uint4 v = *(const uint4*)&Wtfc[(size_t)(n0 + row) * DM_ + k0 + slot * 8];
            *(uint4*)((char*)Bs + row * 128 + ((slot * 16) ^ ((row & 7) << 4))) = v;
        }
        __syncthreads();
#pragma unroll
        for (int es = 0; es < 2; es++) {
            bf16x8 af[4], bg[4];
#pragma unroll
            for (int fi = 0; fi < 4; fi++) af[fi] = ld_frag(As, wr * 64 + fi * 16 + lr, es * 4 + lg);
#pragma unroll
            for (int fj = 0; fj < 4; fj++) bg[fj] = ld_frag(Bs, wc * 64 + fj * 16 + lr, es * 4 + lg);
#pragma unroll
            for (int fi = 0; fi < 4; fi++)
#pragma unroll
                for (int fj = 0; fj < 4; fj++)
                    acc[fi][fj] = __builtin_amdgcn_mfma_f32_16x16x32_bf16(af[fi], bg[fj], acc[fi][fj], 0, 0, 0);
        }
        __syncthreads();
    }
#pragma unroll
    for (int fi = 0; fi < 4; fi++)
#pragma unroll
        for (int fj = 0; fj < 4; fj++)
#pragma unroll
            for (int r = 0; r < 4; r++) {
                int row = m0 + wr * 64 + fi * 16 + lg * 4 + r;
                int col = n0 + wc * 64 + fj * 16 + lr;
                size_t idx = ((size_t)b * S_ + row) * DM_ + col;
                out[idx] = acc[fi][fj][r] + resid[idx];
            }
}

// ---------------------------------------------------------------------------
// In-place LayerNorm over last dim (512). One block (512 thr) per row.
// ---------------------------------------------------------------------------
__global__ __launch_bounds__(512) void k_ln(
    float* __restrict__ out, const float* __restrict__ gamma, const float* __restrict__ beta)
{
    __shared__ float r1[8], r2[8];
    const int row = blockIdx.x;
    const int t   = threadIdx.x;
    float x  = out[(size_t)row * DM_ + t];
    float s1 = x, s2 = x * x;
#pragma unroll
    for (int o = 32; o > 0; o >>= 1) {
        s1 += __shfl_xor(s1, o);
        s2 += __shfl_xor(s2, o);
    }
    const int lane = t & 63, w = t >> 6;
    if (lane == 0) { r1[w] = s1; r2[w] = s2; }
    __syncthreads();
    float tot1 = 0.f, tot2 = 0.f;
#pragma unroll
    for (int i = 0; i < 8; i++) { tot1 += r1[i]; tot2 += r2[i]; }
    const float mu   = tot1 * (1.0f / 512.0f);
    const float var  = tot2 * (1.0f / 512.0f) - mu * mu;
    const float rstd = rsqrtf(var + 1e-5f);
    out[(size_t)row * DM_ + t] = (x - mu) * rstd * gamma[t] + beta[t];
}

// ---------------------------------------------------------------------------
extern "C" void kernel_launch(void* const* d_in, const int* in_sizes, int n_in,
                              void* d_out, int out_size, void* d_ws, size_t ws_size,
                              hipStream_t stream)
{
    const float*         inQ   = (const float*)d_in[0];
    const float*         inK   = (const float*)d_in[1];
    const float*         inV   = (const float*)d_in[2];
    const unsigned char* mask  = (const unsigned char*)d_in[3];
    const float*         res   = (const float*)d_in[4];
    const float*         Wq    = (const float*)d_in[5];
    const float*         Wk    = (const float*)d_in[6];
    const float*         Wv    = (const float*)d_in[7];
    const float*         Wfc   = (const float*)d_in[8];
    const float*         gamma = (const float*)d_in[9];
    const float*         beta  = (const float*)d_in[10];

    float* out    = (float*)d_out;                      // B*S*DM
    float* scores = out + (size_t)B_ * S_ * DM_;        // B*H*S*S

    unsigned short* us   = (unsigned short*)d_ws;
    unsigned short* Wtq  = us;                              // 262144 each
    unsigned short* Wtk  = Wtq + 262144;
    unsigned short* Wtv  = Wtk + 262144;
    unsigned short* Wtfc = Wtv + 262144;
    unsigned short* Qp   = us + 1048576;                    // 4,194,304 each
    unsigned short* Kp   = Qp + 4194304;
    unsigned short* Vp   = Kp + 4194304;
    unsigned short* Vt   = Vp + 4194304;
    unsigned short* Ctx  = Vt + 4194304;
    float* pm     = (float*)(Ctx + 4194304);                // 4*128*512
    float* ps     = pm + 262144;
    float* colm   = ps + 262144;                            // 128*512
    float* colinv = colm + 65536;
    // total ~46.7 MB

    hipLaunchKernelGGL(k_cast_wt,   dim3(8, 8, 4),   dim3(256), 0, stream,
                       Wq, Wk, Wv, Wfc, Wtq, Wtk, Wtv, Wtfc);
    hipLaunchKernelGGL(k_proj,      dim3(4, 4, 48),  dim3(256), 0, stream,
                       inQ, inK, inV, Wtq, Wtk, Wtv, Qp, Kp, Vp);
    hipLaunchKernelGGL(k_tv,        dim3(8, 128),    dim3(256), 0, stream, Vp, Vt);
    hipLaunchKernelGGL(k_scores,    dim3(4, 4, 128), dim3(256), 0, stream,
                       Qp, Kp, res, mask, scores, pm, ps);
    hipLaunchKernelGGL(k_sm_combine, dim3(256),      dim3(256), 0, stream,
                       pm, ps, colm, colinv);
    hipLaunchKernelGGL(k_ctx,       dim3(2, 128),    dim3(256), 0, stream,
                       scores, Vt, colm, colinv, Ctx);
    hipLaunchKernelGGL(k_outproj,   dim3(4, 4, 16),  dim3(256), 0, stream,
                       Ctx, Wtfc, inQ, out);
    hipLaunchKernelGGL(k_ln,        dim3(8192),      dim3(512), 0, stream,
                       out, gamma, beta);
}